// Round 1
// baseline (2085.148 us; speedup 1.0000x reference)
//
#include <hip/hip_runtime.h>
#include <hip/hip_bf16.h>
#include <math.h>

#define B_SZ   8192
#define P_SZ   4
#define L_SZ   (B_SZ * P_SZ)
#define V_SZ   100000
#define D_SZ   128
#define NS_SZ  26
#define ND_SZ  13
#define NEMB   27              // 1 dense + 26 pooled
#define N_PAIR 351             // 27*26/2
#define X_DIM  479             // 128 + 351

// ---------------------------------------------------------------------------
// Bottom MLP layer 1: (B x 13) @ (13 x 512) + bias, ReLU. One block per row.
// ---------------------------------------------------------------------------
__global__ __launch_bounds__(512) void bottom1_kernel(
    const float* __restrict__ dx, const float* __restrict__ W,
    const float* __restrict__ bias, float* __restrict__ out)
{
    __shared__ float row[ND_SZ];
    int b = blockIdx.x;
    int t = threadIdx.x;
    if (t < ND_SZ) row[t] = dx[b * ND_SZ + t];
    __syncthreads();
    float sum = bias[t];
#pragma unroll
    for (int k = 0; k < ND_SZ; k++)
        sum += row[k] * W[k * 512 + t];
    out[(size_t)b * 512 + t] = fmaxf(sum, 0.0f);
}

// ---------------------------------------------------------------------------
// Generic fp32 GEMM: C[M x N] = act(A[M x K] @ W[K x N] + bias), strided C.
// 64x64 tile, 256 threads, 4x4 micro-tile, BK=16. M,N multiples of 64; K any.
// ---------------------------------------------------------------------------
#define BM 64
#define BN 64
#define BK 16

__global__ __launch_bounds__(256) void gemm_bias_act(
    const float* __restrict__ A, const float* __restrict__ W,
    const float* __restrict__ bias, float* __restrict__ C,
    int M, int N, int K, int lda, int ldb, int ldc, int do_relu)
{
    __shared__ float As[BK][BM + 1];   // [16][65] — pad kills write conflicts
    __shared__ float Bs[BK][BN + 1];

    int bm = blockIdx.y * BM;
    int bn = blockIdx.x * BN;
    int t  = threadIdx.x;
    int tm = (t % 16) * 4;
    int tn = (t / 16) * 4;

    float acc[4][4] = {};

    for (int k0 = 0; k0 < K; k0 += BK) {
        // A tile: 64 rows x 16 cols
#pragma unroll
        for (int i = t; i < BM * BK; i += 256) {
            int r = i / BK, c = i % BK;
            int gk = k0 + c;
            As[c][r] = (gk < K) ? A[(size_t)(bm + r) * lda + gk] : 0.0f;
        }
        // W tile: 16 rows x 64 cols (coalesced)
#pragma unroll
        for (int i = t; i < BK * BN; i += 256) {
            int r = i / BN, c = i % BN;
            int gk = k0 + r;
            Bs[r][c] = (gk < K) ? W[(size_t)gk * ldb + (bn + c)] : 0.0f;
        }
        __syncthreads();
#pragma unroll
        for (int kk = 0; kk < BK; kk++) {
            float a[4], bvals[4];
#pragma unroll
            for (int i = 0; i < 4; i++) a[i] = As[kk][tm + i];
#pragma unroll
            for (int j = 0; j < 4; j++) bvals[j] = Bs[kk][tn + j];
#pragma unroll
            for (int i = 0; i < 4; i++)
#pragma unroll
                for (int j = 0; j < 4; j++)
                    acc[i][j] += a[i] * bvals[j];
        }
        __syncthreads();
    }

#pragma unroll
    for (int i = 0; i < 4; i++) {
        int row = bm + tm + i;
#pragma unroll
        for (int j = 0; j < 4; j++) {
            int col = bn + tn + j;
            float v = acc[i][j] + bias[col];
            if (do_relu) v = fmaxf(v, 0.0f);
            C[(size_t)row * ldc + col] = v;
        }
    }
}

// ---------------------------------------------------------------------------
// Embedding bag pooling (sum over P=4 consecutive rows). One block = (s, b).
// Writes rows 1..26 of all_embs[b] (row 0 is dense_out, written by GEMM L3).
// ---------------------------------------------------------------------------
__global__ __launch_bounds__(128) void emb_pool_kernel(
    const int* __restrict__ sx, const int* __restrict__ soff,
    const float* __restrict__ tables, float* __restrict__ all_embs)
{
    int s = blockIdx.x;   // sparse feature
    int b = blockIdx.y;   // bag
    int d = threadIdx.x;  // 0..127
    int start = soff[b];
    int end   = (b + 1 < B_SZ) ? soff[b + 1] : L_SZ;
    const float* tab = tables + (size_t)s * V_SZ * D_SZ;
    float sum = 0.0f;
    for (int l = start; l < end; l++) {
        int idx = sx[(size_t)l * NS_SZ + s];
        sum += tab[(size_t)idx * D_SZ + d];
    }
    all_embs[((size_t)b * NEMB + 1 + s) * D_SZ + d] = sum;
}

// ---------------------------------------------------------------------------
// Pairwise interaction: per row, Gram(27x128), triu(k=1) in row-major order,
// concat [dense_out(128), triu(351)] -> x[b][0..478]. One block per row.
// ---------------------------------------------------------------------------
__global__ __launch_bounds__(256) void interact_kernel(
    const float* __restrict__ all_embs, float* __restrict__ x)
{
    __shared__ float e[NEMB * 129];   // pad 128->129 breaks bank aliasing
    int b = blockIdx.x;
    int t = threadIdx.x;
    const float* src = all_embs + (size_t)b * (NEMB * D_SZ);
    for (int i = t; i < NEMB * D_SZ; i += 256) {
        int r = i >> 7, c = i & 127;
        e[r * 129 + c] = src[i];
    }
    __syncthreads();
    float* xb = x + (size_t)b * X_DIM;
    if (t < D_SZ) xb[t] = e[t];   // dense_out copy (row 0)
    for (int p = t; p < N_PAIR; p += 256) {
        // map p -> (i, j) in np.triu_indices(27, 1) row-major order
        int i = 0, rem = p;
        while (rem >= NS_SZ - i) { rem -= NS_SZ - i; i++; }
        int j = i + 1 + rem;
        const float* ei = e + i * 129;
        const float* ej = e + j * 129;
        float sum = 0.0f;
#pragma unroll 8
        for (int k = 0; k < D_SZ; k++) sum += ei[k] * ej[k];
        xb[D_SZ + p] = sum;
    }
}

// ---------------------------------------------------------------------------
// Top MLP layer 3: (B x 256) @ (256 x 1) + bias, sigmoid. One block per row.
// ---------------------------------------------------------------------------
__global__ __launch_bounds__(256) void top3_kernel(
    const float* __restrict__ t2, const float* __restrict__ w,
    const float* __restrict__ bias, float* __restrict__ out)
{
    __shared__ float wsum[4];
    int b = blockIdx.x;
    int t = threadIdx.x;
    float v = t2[(size_t)b * 256 + t] * w[t];
#pragma unroll
    for (int o = 32; o > 0; o >>= 1) v += __shfl_down(v, o, 64);
    if ((t & 63) == 0) wsum[t >> 6] = v;
    __syncthreads();
    if (t == 0) {
        float s = wsum[0] + wsum[1] + wsum[2] + wsum[3] + bias[0];
        out[b] = 1.0f / (1.0f + expf(-s));
    }
}

// ---------------------------------------------------------------------------
extern "C" void kernel_launch(void* const* d_in, const int* in_sizes, int n_in,
                              void* d_out, int out_size, void* d_ws, size_t ws_size,
                              hipStream_t stream)
{
    const float* dense_x  = (const float*)d_in[0];
    const int*   sparse_x = (const int*)  d_in[1];
    const int*   soff     = (const int*)  d_in[2];
    const float* emb_tab  = (const float*)d_in[3];
    const float* bw1 = (const float*)d_in[4];
    const float* bb1 = (const float*)d_in[5];
    const float* bw2 = (const float*)d_in[6];
    const float* bb2 = (const float*)d_in[7];
    const float* bw3 = (const float*)d_in[8];
    const float* bb3 = (const float*)d_in[9];
    const float* tw1 = (const float*)d_in[10];
    const float* tb1 = (const float*)d_in[11];
    const float* tw2 = (const float*)d_in[12];
    const float* tb2 = (const float*)d_in[13];
    const float* tw3 = (const float*)d_in[14];
    const float* tb3 = (const float*)d_in[15];
    float* out = (float*)d_out;

    // workspace layout (bytes)
    char* ws = (char*)d_ws;
    float* all_embs = (float*)ws;                                   // 8192*27*128*4 = 113,246,208
    float* h1       = (float*)(ws + 113246208);                     // 8192*512*4   = 16,777,216
    float* h2       = (float*)(ws + 113246208 + 16777216);          // 8192*256*4   =  8,388,608
    float* x        = (float*)(ws + 113246208 + 16777216 + 8388608);// 8192*479*4   = 15,695,872
    float* t1 = h1;   // bottom h1 dead before top layer 1 runs
    float* t2 = h2;   // bottom h2 dead before top layer 2 runs

    // 1. bottom MLP layer 1: (8192x13) -> 512
    bottom1_kernel<<<B_SZ, 512, 0, stream>>>(dense_x, bw1, bb1, h1);
    // 2. bottom layer 2: (8192x512) @ (512x256)
    gemm_bias_act<<<dim3(256 / BN, B_SZ / BM), 256, 0, stream>>>(
        h1, bw2, bb2, h2, B_SZ, 256, 512, 512, 256, 256, 1);
    // 3. bottom layer 3: (8192x256) @ (256x128) -> all_embs row 0 (ldc=3456)
    gemm_bias_act<<<dim3(128 / BN, B_SZ / BM), 256, 0, stream>>>(
        h2, bw3, bb3, all_embs, B_SZ, 128, 256, 256, 128, NEMB * D_SZ, 1);
    // 4. embedding pooling -> all_embs rows 1..26
    emb_pool_kernel<<<dim3(NS_SZ, B_SZ), 128, 0, stream>>>(
        sparse_x, soff, emb_tab, all_embs);
    // 5. interaction + concat -> x (8192 x 479)
    interact_kernel<<<B_SZ, 256, 0, stream>>>(all_embs, x);
    // 6. top layer 1: (8192x479) @ (479x512)
    gemm_bias_act<<<dim3(512 / BN, B_SZ / BM), 256, 0, stream>>>(
        x, tw1, tb1, t1, B_SZ, 512, X_DIM, X_DIM, 512, 512, 1);
    // 7. top layer 2: (8192x512) @ (512x256)
    gemm_bias_act<<<dim3(256 / BN, B_SZ / BM), 256, 0, stream>>>(
        t1, tw2, tb2, t2, B_SZ, 256, 512, 512, 256, 256, 1);
    // 8. top layer 3: (8192x256) @ (256x1) + sigmoid
    top3_kernel<<<B_SZ, 256, 0, stream>>>(t2, tw3, tb3, out);
}